// Round 4
// baseline (148.216 us; speedup 1.0000x reference)
//
#include <hip/hip_runtime.h>

// Multi-scale deformable attention forward.
// value:              (N, Lin, nH, D)        float32
// spatial_shapes:     (L, 2)                 int32/int64 (runtime-detected)
// level_start_index:  (L,)                   int32/int64 (runtime-detected)
// sampling_locations: (N, Lq, nH, L, P, 2)   float32
// attention_weights:  (N, Lq, nH, L, P)      float32
// out:                (N, Lq, nH*D)          float32
#define NH 8
#define DD 32
#define LL 4
#define PP 4
#define STAGE_BYTES 43072   // levels 2+3 for the 92/46/23/12 pyramid

typedef float  f32x4  __attribute__((ext_vector_type(4)));
typedef float  f32x2  __attribute__((ext_vector_type(2)));
typedef int    i32x4  __attribute__((ext_vector_type(4)));
typedef _Float16 half4v __attribute__((ext_vector_type(4)));

// ---------------- prepass: value (n,pos,h,d) fp32 -> (n,h,pos,d) fp16 ----------------
// XCD-pinned like the main kernel so each vh slab is written by the XCD
// that will gather from it -> L2-warm at msda start.
__global__ __launch_bounds__(256) void conv_kernel(
    const float* __restrict__ value, _Float16* __restrict__ vh,
    int Lin, int spx, int nSlabs)
{
    const int xcd  = blockIdx.x & 7;
    const int blk  = blockIdx.x >> 3;
    const int sw   = blk % spx;
    const int seg  = blk / spx;
    const int slab = xcd * spx + sw;
    if (slab >= nSlabs) return;
    const int i = seg * 256 + threadIdx.x;          // over Lin*8 chunks
    if (i >= Lin * 8) return;
    const int d4  = i & 7;
    const int pos = i >> 3;
    const int n   = slab >> 3;
    const int h   = slab & 7;

    const f32x4 v = __builtin_nontemporal_load(
        (const f32x4*)(value + (((size_t)n * Lin + pos) * NH + h) * DD + d4 * 4));
    half4v o;
    o.x = (_Float16)v.x; o.y = (_Float16)v.y; o.z = (_Float16)v.z; o.w = (_Float16)v.w;
    // NOT nontemporal: vh must stay resident in this XCD's L2 for the gathers.
    *(half4v*)(vh + ((size_t)slab * Lin + pos) * DD + d4 * 4) = o;
}

// acc(f32) += f16(lo/hi half of DW) * W(f32)  — single v_fma_mix_f32.
#define FMAMIX_LO(ACC, DW, W) \
    asm("v_fma_mix_f32 %0, %1, %2, %0 op_sel:[0,0,0] op_sel_hi:[1,0,0]" \
        : "+v"(ACC) : "v"(DW), "v"(W))
#define FMAMIX_HI(ACC, DW, W) \
    asm("v_fma_mix_f32 %0, %1, %2, %0 op_sel:[1,0,0] op_sel_hi:[1,0,0]" \
        : "+v"(ACC) : "v"(DW), "v"(W))

#define SB() __builtin_amdgcn_sched_barrier(0)

// ---------------- main kernel ----------------
// R9: L2 scattered-request throughput is the wall (R3: MLP abundant by
// Little's law, deeper pipeline gave only ~5%). Levels 2+3 are contiguous
// [S2, Lin) = 43072 B/slab -> stage them in LDS per block and serve HALF
// of all gathers from LDS (points of groups 2,3). Scattered L2 traffic
// 737 MB -> 369 MB + 242 MB friendly streaming. LDS 63040 B -> 2 blocks/CU
// (8 waves); MLP per CU still ~28x over the halved scatter demand.
// Global groups 0,1 keep the R8 16-deep pipeline; their latency hides
// under the LDS-served work.
__global__ __attribute__((amdgpu_flat_work_group_size(256, 256)))
__attribute__((amdgpu_waves_per_eu(2)))
void msda_fwd_h(
    const _Float16* __restrict__ vh,
    const int*   __restrict__ ssh,
    const int*   __restrict__ lsi,
    const float* __restrict__ sloc,
    const float* __restrict__ aw,
    float*       __restrict__ out,
    int N, int Lq, int Lin, int spx, int nSlabs)
{
    __shared__ i32x4 ent[32 * 39];                 // 19968 B
    __shared__ i32x4 stage4[STAGE_BYTES / 16];     // 43072 B  (total 63040)

    const int xcd   = blockIdx.x & 7;
    const int blk   = blockIdx.x >> 3;
    const int sw    = blk % spx;
    const int chunk = blk / spx;
    const int slab  = xcd * spx + sw;          // n*NH + h  (block-uniform)
    if (slab >= nSlabs) return;                // uniform -> barrier-safe

    const int t  = threadIdx.x;
    const int u  = t >> 3;                     // unit (query) within block
    const int j  = t & 7;
    const int q  = chunk * 32 + u;
    const int qc = min(q, Lq - 1);
    const int n  = slab >> 3;
    const int h  = slab & 7;

    const bool is64 = (ssh[1] == 0);
    const int  S2v  = is64 ? lsi[4] : lsi[2];          // start of level 2
    const int  stB  = (Lin - S2v) * (DD * 2);          // bytes of levels 2+3
    const bool staged = (stB > 0) && (stB <= STAGE_BYTES);

    // ---- stage levels 2+3 into LDS (contiguous tail of the slab) ----
    if (staged) {
        const char* src = (const char*)vh + ((size_t)slab * Lin + S2v) * (DD * 2);
        i32x4 tmp[11];
#pragma unroll
        for (int k = 0; k < 11; ++k) {
            const int off = t * 16 + k * 4096;
            if (off < stB) tmp[k] = *(const i32x4*)(src + off);
        }
#pragma unroll
        for (int k = 0; k < 11; ++k) {
            const int off = t * 16 + k * 4096;
            if (off < stB) *(i32x4*)((char*)stage4 + off) = tmp[k];
        }
    }

    // ---- phase 1: points p = 2j, 2j+1 of unit u (both sides) ----
    {
        const size_t nqh = ((size_t)n * Lq + qc) * NH + h;
        const int l = j >> 1;                  // both points share a level
        const int W = is64 ? ssh[4 * l + 2] : ssh[2 * l + 1];
        const int H = is64 ? ssh[4 * l]     : ssh[2 * l];
        const int S = is64 ? lsi[2 * l]     : lsi[l];
        const f32x4 lc = __builtin_nontemporal_load((const f32x4*)sloc + nqh * 8 + j);
        const f32x2 av = __builtin_nontemporal_load((const f32x2*)aw + nqh * 8 + j);
        const float fW = (float)W, fH = (float)H;
        const int rowb  = W * (DD * 2);
        // staged levels (j>=4): offsets relative to S2 -> direct LDS offsets
        const int sbase = (staged && j >= 4) ? (S - S2v) * (DD * 2) : S * (DD * 2);
#pragma unroll
        for (int pt = 0; pt < 2; ++pt) {
            const float x  = lc[2 * pt]     * fW - 0.5f;
            const float y  = lc[2 * pt + 1] * fH - 0.5f;
            const float wq = av[pt];
            const float x0f = floorf(x), y0f = floorf(y);
            const int x0 = (int)x0f, y0 = (int)y0f;
            const float dx = x - x0f, dy = y - y0f;
            const int x1 = x0 + 1, y1 = y0 + 1;
            const bool vx0 = (x0 >= 0) & (x0 < W), vx1 = (x1 >= 0) & (x1 < W);
            const bool vy0 = (y0 >= 0) & (y0 < H), vy1 = (y1 >= 0) & (y1 < H);
            const int cx0 = min(max(x0, 0), W - 1), cx1 = min(max(x1, 0), W - 1);
            const int cy0 = min(max(y0, 0), H - 1), cy1 = min(max(y1, 0), H - 1);
            const float wx0 = (1.f - dx) * wq * (vx0 ? 1.f : 0.f);
            const float wx1 = dx         * wq * (vx1 ? 1.f : 0.f);
            const float ty  = (1.f - dy) * (vy0 ? 1.f : 0.f);
            const float by  = dy         * (vy1 ? 1.f : 0.f);
            const int rt = cy0 * rowb + sbase;
            const int rb = cy1 * rowb + sbase;
            i32x4 e0, e1;
            e0.x = rt + cx0 * (DD * 2);  e0.y = rb + cx0 * (DD * 2);
            e0.z = __float_as_int(wx0 * ty);  e0.w = __float_as_int(wx0 * by);
            e1.x = rt + cx1 * (DD * 2);  e1.y = rb + cx1 * (DD * 2);
            e1.z = __float_as_int(wx1 * ty);  e1.w = __float_as_int(wx1 * by);
            const int base = u * 39 + 5 * j + 2 * pt;
            ent[base]     = e0;
            ent[base + 1] = e1;
        }
    }
    __syncthreads();
    if (q >= Lq) return;

    // ---- phase 2 ----
    const int side = j >> 2;
    const int cg   = j & 3;
    const char* __restrict__ sb =
        (const char*)vh + (size_t)slab * Lin * (DD * 2) + cg * 16;  // saddr + lane base
    const char* __restrict__ stg = (const char*)stage4 + cg * 16;
    const int ub = u * 39 + side;

    float acc[8];
#pragma unroll
    for (int k = 0; k < 8; ++k) acc[k] = 0.f;

    // entry for point p=4b+i: idx = ub + 10b + {0,2,5,7}[i]
#define RD(b, E) { \
    E[0] = ent[ub + 10 * (b) + 0]; \
    E[1] = ent[ub + 10 * (b) + 2]; \
    E[2] = ent[ub + 10 * (b) + 5]; \
    E[3] = ent[ub + 10 * (b) + 7]; }
#define LD(E, V) _Pragma("unroll") \
    for (int i = 0; i < 4; ++i) { \
        V[2*i]   = *(const i32x4*)(sb + (unsigned)E[i].x); \
        V[2*i+1] = *(const i32x4*)(sb + (unsigned)E[i].y); }
#define LLD(E, V) _Pragma("unroll") \
    for (int i = 0; i < 4; ++i) { \
        V[2*i]   = *(const i32x4*)(stg + (unsigned)E[i].x); \
        V[2*i+1] = *(const i32x4*)(stg + (unsigned)E[i].y); }
#define AC(E, V) _Pragma("unroll") \
    for (int i = 0; i < 4; ++i) { \
        const float wt = __int_as_float(E[i].z); \
        const float wb = __int_as_float(E[i].w); \
        _Pragma("unroll") for (int d = 0; d < 4; ++d) { \
            FMAMIX_LO(acc[2*d],   V[2*i][d],   wt); \
            FMAMIX_HI(acc[2*d+1], V[2*i][d],   wt); \
            FMAMIX_LO(acc[2*d],   V[2*i+1][d], wb); \
            FMAMIX_HI(acc[2*d+1], V[2*i+1][d], wb); } }

    i32x4 E0[4], E1[4], E2[4], E3[4];
    i32x4 V0[8], V1[8];
    RD(0, E0) RD(1, E1)            // 8 ds_read_b128 (entries, levels 0,1)
    SB();
    LD(E0, V0) LD(E1, V1)          // 16 global_load_dwordx4 outstanding
    SB();
    if (staged) {
        // serve levels 2,3 from LDS while the global loads fly
        i32x4 VL[8];
        RD(2, E2)
        LLD(E2, VL)
        AC(E2, VL)
        RD(3, E3)
        LLD(E3, VL)
        AC(E3, VL)
        SB();
        AC(E0, V0)
        AC(E1, V1)
    } else {
        // fallback: all-global pipeline (R8 schedule)
        AC(E0, V0)
        RD(2, E2)
        SB();
        LD(E2, V0)
        SB();
        AC(E1, V1)
        RD(3, E3)
        SB();
        LD(E3, V1)
        SB();
        AC(E2, V0)
        AC(E3, V1)
    }

    // merge x0/x1 partials: partner lane is j ^ 4
#pragma unroll
    for (int k = 0; k < 8; ++k)
        acc[k] += __shfl_xor(acc[k], 4);

    f32x4 st;
    st.x = acc[side * 4 + 0];
    st.y = acc[side * 4 + 1];
    st.z = acc[side * 4 + 2];
    st.w = acc[side * 4 + 3];
    const size_t onqh = ((size_t)n * Lq + q) * NH + h;
    __builtin_nontemporal_store(st, (f32x4*)(out + onqh * DD + cg * 8 + side * 4));
}

// ---------------- fp32 fallback if ws too small ----------------
__global__ __launch_bounds__(256) void msda_fwd_f32(
    const float* __restrict__ value,
    const int*   __restrict__ spatial_shapes,
    const int*   __restrict__ level_start,
    const float* __restrict__ sloc,
    const float* __restrict__ aw,
    float*       __restrict__ out,
    int N, int Lq, int Lin, int total)
{
    int tid = blockIdx.x * blockDim.x + threadIdx.x;
    if (tid >= total) return;
    const int c  = tid & 7;
    const int h  = (tid >> 3) & 7;
    const int nq = tid >> 6;
    const int n  = nq / Lq;
    const bool is64 = (spatial_shapes[1] == 0);
    int Hs[LL], Ws[LL], Ss[LL];
#pragma unroll
    for (int l = 0; l < LL; ++l) {
        if (is64) { Hs[l] = spatial_shapes[4*l]; Ws[l] = spatial_shapes[4*l+2]; Ss[l] = level_start[2*l]; }
        else      { Hs[l] = spatial_shapes[2*l]; Ws[l] = spatial_shapes[2*l+1]; Ss[l] = level_start[l]; }
    }
    const size_t nqh = (size_t)nq * NH + h;
    const float* loc_p = sloc + nqh * (LL * PP * 2);
    const float* aw_p  = aw   + nqh * (LL * PP);
    float4 acc = make_float4(0.f, 0.f, 0.f, 0.f);
#pragma unroll
    for (int l = 0; l < LL; ++l) {
        const int H = Hs[l], W = Ws[l];
        const float* vb = value + (((size_t)n * Lin + Ss[l]) * NH + h) * DD + c * 4;
#pragma unroll
        for (int p = 0; p < PP; ++p) {
            const int jj = l * PP + p;
            const float x = loc_p[2*jj] * (float)W - 0.5f;
            const float y = loc_p[2*jj+1] * (float)H - 0.5f;
            const float w = aw_p[jj];
            const float x0f = floorf(x), y0f = floorf(y);
            const int x0 = (int)x0f, y0 = (int)y0f, x1 = x0+1, y1 = y0+1;
            const float dx = x - x0f, dy = y - y0f;
            const bool vx0 = x0>=0 && x0<W, vx1 = x1>=0 && x1<W;
            const bool vy0 = y0>=0 && y0<H, vy1 = y1>=0 && y1<H;
            const int cx0 = min(max(x0,0),W-1), cx1 = min(max(x1,0),W-1);
            const int cy0 = min(max(y0,0),H-1), cy1 = min(max(y1,0),H-1);
            const float w00 = (1.f-dx)*(1.f-dy)*w*((vx0&&vy0)?1.f:0.f);
            const float w01 = dx*(1.f-dy)*w*((vx1&&vy0)?1.f:0.f);
            const float w10 = (1.f-dx)*dy*w*((vx0&&vy1)?1.f:0.f);
            const float w11 = dx*dy*w*((vx1&&vy1)?1.f:0.f);
            const float4 v00 = *(const float4*)(vb + (size_t)(cy0*W+cx0)*(NH*DD));
            const float4 v01 = *(const float4*)(vb + (size_t)(cy0*W+cx1)*(NH*DD));
            const float4 v10 = *(const float4*)(vb + (size_t)(cy1*W+cx0)*(NH*DD));
            const float4 v11 = *(const float4*)(vb + (size_t)(cy1*W+cx1)*(NH*DD));
            acc.x += w00*v00.x + w01*v01.x + w10*v10.x + w11*v11.x;
            acc.y += w00*v00.y + w01*v01.y + w10*v10.y + w11*v11.y;
            acc.z += w00*v00.z + w01*v01.z + w10*v10.z + w11*v11.z;
            acc.w += w00*v00.w + w01*v01.w + w10*v10.w + w11*v11.w;
        }
    }
    *(float4*)(out + nqh * DD + c * 4) = acc;
}

extern "C" void kernel_launch(void* const* d_in, const int* in_sizes, int n_in,
                              void* d_out, int out_size, void* d_ws, size_t ws_size,
                              hipStream_t stream)
{
    const float* value = (const float*)d_in[0];
    const int*   ss    = (const int*)  d_in[1];
    const int*   lsi   = (const int*)  d_in[2];
    const float* sloc  = (const float*)d_in[3];
    const float* aw    = (const float*)d_in[4];
    float* out = (float*)d_out;

    const int N = 2;
    const int Lq  = in_sizes[4] / (N * NH * LL * PP);
    const int Lin = in_sizes[0] / (N * NH * DD);

    const size_t need = (size_t)N * NH * Lin * DD * sizeof(_Float16);
    if (ws_size >= need) {
        _Float16* vh = (_Float16*)d_ws;
        const int nSlabs = N * NH;              // 16
        const int spx    = (nSlabs + 7) / 8;    // slabs per XCD = 2
        const int segs   = (Lin * 8 + 255) / 256;
        conv_kernel<<<8 * spx * segs, 256, 0, stream>>>(value, vh, Lin, spx, nSlabs);

        const int chunks = (Lq + 31) / 32;
        const int grid   = 8 * spx * chunks;
        msda_fwd_h<<<grid, 256, 0, stream>>>(vh, ss, lsi, sloc, aw, out,
                                             N, Lq, Lin, spx, nSlabs);
    } else {
        const int total = N * Lq * NH * 8;
        msda_fwd_f32<<<(total + 255) / 256, 256, 0, stream>>>(value, ss, lsi, sloc, aw, out,
                                                              N, Lq, Lin, total);
    }
}

// Round 5
// 131.460 us; speedup vs baseline: 1.1275x; 1.1275x over previous
//
#include <hip/hip_runtime.h>

// Multi-scale deformable attention forward.
// value:              (N, Lin, nH, D)        float32
// spatial_shapes:     (L, 2)                 int32/int64 (runtime-detected)
// level_start_index:  (L,)                   int32/int64 (runtime-detected)
// sampling_locations: (N, Lq, nH, L, P, 2)   float32
// attention_weights:  (N, Lq, nH, L, P)      float32
// out:                (N, Lq, nH*D)          float32
#define NH 8
#define DD 32
#define LL 4
#define PP 4

typedef float  f32x4  __attribute__((ext_vector_type(4)));
typedef float  f32x2  __attribute__((ext_vector_type(2)));
typedef int    i32x4  __attribute__((ext_vector_type(4)));
typedef _Float16 half4v __attribute__((ext_vector_type(4)));

// ---------------- prepass: value (n,pos,h,d) fp32 -> (n,h,pos,d) fp16 ----------------
// XCD-pinned like the main kernel so each vh slab is written by the XCD
// that will gather from it -> L2-warm at msda start.
__global__ __launch_bounds__(256) void conv_kernel(
    const float* __restrict__ value, _Float16* __restrict__ vh,
    int Lin, int spx, int nSlabs)
{
    const int xcd  = blockIdx.x & 7;
    const int blk  = blockIdx.x >> 3;
    const int sw   = blk % spx;
    const int seg  = blk / spx;
    const int slab = xcd * spx + sw;
    if (slab >= nSlabs) return;
    const int i = seg * 256 + threadIdx.x;          // over Lin*8 chunks
    if (i >= Lin * 8) return;
    const int d4  = i & 7;
    const int pos = i >> 3;
    const int n   = slab >> 3;
    const int h   = slab & 7;

    const f32x4 v = __builtin_nontemporal_load(
        (const f32x4*)(value + (((size_t)n * Lin + pos) * NH + h) * DD + d4 * 4));
    half4v o;
    o.x = (_Float16)v.x; o.y = (_Float16)v.y; o.z = (_Float16)v.z; o.w = (_Float16)v.w;
    // NOT nontemporal: vh must stay resident in this XCD's L2 for the gathers.
    *(half4v*)(vh + ((size_t)slab * Lin + pos) * DD + d4 * 4) = o;
}

// acc(f32) += f16(lo/hi half of DW) * W(f32)  — single v_fma_mix_f32.
#define FMAMIX_LO(ACC, DW, W) \
    asm("v_fma_mix_f32 %0, %1, %2, %0 op_sel:[0,0,0] op_sel_hi:[1,0,0]" \
        : "+v"(ACC) : "v"(DW), "v"(W))
#define FMAMIX_HI(ACC, DW, W) \
    asm("v_fma_mix_f32 %0, %1, %2, %0 op_sel:[1,0,0] op_sel_hi:[1,0,0]" \
        : "+v"(ACC) : "v"(DW), "v"(W))

#define SB() __builtin_amdgcn_sched_barrier(0)

// ---------------- main kernel ----------------
// Block = one (n,h) slab x 32 queries; blockIdx%8 -> XCD so each XCD's L2
// holds only 2 slabs (1.44 MB) -> gathers stay L2-hit (FETCH at stream floor).
// R10: REVERT R9's LDS staging (occupancy 48->18%, 1.6M bank conflicts,
// serial 43KB copy -> msda 42->59us). Single new variable vs R3:
// slab-major block order (sw = blk/chunks, not blk%chunks) so consecutive
// blocks on an XCD process the SAME slab -> each CU's 32KB L1 holds one
// slab's level-3 (9KB) + much of level-2 (34KB) instead of thrashing
// between two slabs' 86KB. Level-3: 128 samples/block over 144 cells ->
// real temporal reuse for L1 to capture.
// Phase 2 keeps the R8 16-deep pinned pipeline (sched_barrier fences).
__global__ __attribute__((amdgpu_flat_work_group_size(256, 256)))
__attribute__((amdgpu_waves_per_eu(4)))
void msda_fwd_h(
    const _Float16* __restrict__ vh,
    const int*   __restrict__ ssh,
    const int*   __restrict__ lsi,
    const float* __restrict__ sloc,
    const float* __restrict__ aw,
    float*       __restrict__ out,
    int N, int Lq, int Lin, int spx, int chunks, int nSlabs)
{
    __shared__ i32x4 ent[32 * 39];   // 19968 B

    const int xcd   = blockIdx.x & 7;
    const int blk   = blockIdx.x >> 3;
    const int sw    = blk / chunks;            // slab-major: one slab at a time per XCD
    const int chunk = blk % chunks;
    const int slab  = xcd * spx + sw;          // n*NH + h  (block-uniform)
    if (slab >= nSlabs) return;                // uniform -> barrier-safe

    const int t  = threadIdx.x;
    const int u  = t >> 3;                     // unit (query) within block
    const int j  = t & 7;
    const int q  = chunk * 32 + u;
    const int qc = min(q, Lq - 1);
    const int n  = slab >> 3;
    const int h  = slab & 7;

    // ---- phase 1: points p = 2j, 2j+1 of unit u (both sides) ----
    {
        const size_t nqh = ((size_t)n * Lq + qc) * NH + h;
        const int l = j >> 1;                  // both points share a level
        const bool is64 = (ssh[1] == 0);
        const int W = is64 ? ssh[4 * l + 2] : ssh[2 * l + 1];
        const int H = is64 ? ssh[4 * l]     : ssh[2 * l];
        const int S = is64 ? lsi[2 * l]     : lsi[l];
        const f32x4 lc = __builtin_nontemporal_load((const f32x4*)sloc + nqh * 8 + j);
        const f32x2 av = __builtin_nontemporal_load((const f32x2*)aw + nqh * 8 + j);
        const float fW = (float)W, fH = (float)H;
        const int rowb  = W * (DD * 2);
        const int sbase = S * (DD * 2);
#pragma unroll
        for (int pt = 0; pt < 2; ++pt) {
            const float x  = lc[2 * pt]     * fW - 0.5f;
            const float y  = lc[2 * pt + 1] * fH - 0.5f;
            const float wq = av[pt];
            const float x0f = floorf(x), y0f = floorf(y);
            const int x0 = (int)x0f, y0 = (int)y0f;
            const float dx = x - x0f, dy = y - y0f;
            const int x1 = x0 + 1, y1 = y0 + 1;
            const bool vx0 = (x0 >= 0) & (x0 < W), vx1 = (x1 >= 0) & (x1 < W);
            const bool vy0 = (y0 >= 0) & (y0 < H), vy1 = (y1 >= 0) & (y1 < H);
            const int cx0 = min(max(x0, 0), W - 1), cx1 = min(max(x1, 0), W - 1);
            const int cy0 = min(max(y0, 0), H - 1), cy1 = min(max(y1, 0), H - 1);
            const float wx0 = (1.f - dx) * wq * (vx0 ? 1.f : 0.f);
            const float wx1 = dx         * wq * (vx1 ? 1.f : 0.f);
            const float ty  = (1.f - dy) * (vy0 ? 1.f : 0.f);
            const float by  = dy         * (vy1 ? 1.f : 0.f);
            const int rt = cy0 * rowb + sbase;
            const int rb = cy1 * rowb + sbase;
            i32x4 e0, e1;
            e0.x = rt + cx0 * (DD * 2);  e0.y = rb + cx0 * (DD * 2);
            e0.z = __float_as_int(wx0 * ty);  e0.w = __float_as_int(wx0 * by);
            e1.x = rt + cx1 * (DD * 2);  e1.y = rb + cx1 * (DD * 2);
            e1.z = __float_as_int(wx1 * ty);  e1.w = __float_as_int(wx1 * by);
            const int base = u * 39 + 5 * j + 2 * pt;
            ent[base]     = e0;
            ent[base + 1] = e1;
        }
    }
    __syncthreads();
    if (q >= Lq) return;

    // ---- phase 2 ----
    const int side = j >> 2;
    const int cg   = j & 3;
    const char* __restrict__ sb =
        (const char*)vh + (size_t)slab * Lin * (DD * 2) + cg * 16;  // saddr + lane base
    const int ub = u * 39 + side;

    float acc[8];
#pragma unroll
    for (int k = 0; k < 8; ++k) acc[k] = 0.f;

    // entry for point p=4b+i: idx = ub + 10b + {0,2,5,7}[i]
#define RD(b, E) { \
    E[0] = ent[ub + 10 * (b) + 0]; \
    E[1] = ent[ub + 10 * (b) + 2]; \
    E[2] = ent[ub + 10 * (b) + 5]; \
    E[3] = ent[ub + 10 * (b) + 7]; }
#define LD(E, V) _Pragma("unroll") \
    for (int i = 0; i < 4; ++i) { \
        V[2*i]   = *(const i32x4*)(sb + (unsigned)E[i].x); \
        V[2*i+1] = *(const i32x4*)(sb + (unsigned)E[i].y); }
#define AC(E, V) _Pragma("unroll") \
    for (int i = 0; i < 4; ++i) { \
        const float wt = __int_as_float(E[i].z); \
        const float wb = __int_as_float(E[i].w); \
        _Pragma("unroll") for (int d = 0; d < 4; ++d) { \
            FMAMIX_LO(acc[2*d],   V[2*i][d],   wt); \
            FMAMIX_HI(acc[2*d+1], V[2*i][d],   wt); \
            FMAMIX_LO(acc[2*d],   V[2*i+1][d], wb); \
            FMAMIX_HI(acc[2*d+1], V[2*i+1][d], wb); } }

    // R8 schedule: 16 loads in flight, then 8-deep sustained.
    // sched_barrier(0) fences stop the scheduler from collapsing the
    // pipeline to save registers (R1/R2 failure mode).
    i32x4 E0[4], E1[4], E2[4], E3[4];
    i32x4 V0[8], V1[8];
    RD(0, E0) RD(1, E1)        // 8 ds_read_b128
    SB();
    LD(E0, V0) LD(E1, V1)      // 16 global_load_dwordx4 outstanding
    SB();
    AC(E0, V0)                 // waits vmcnt(8)
    RD(2, E2)                  // ds for group 2 under remaining vm latency
    SB();
    LD(E2, V0)                 // refill freed V0 (8 outstanding + V1 pending)
    SB();
    AC(E1, V1)
    RD(3, E3)
    SB();
    LD(E3, V1)
    SB();
    AC(E2, V0)
    AC(E3, V1)

    // merge x0/x1 partials: partner lane is j ^ 4
#pragma unroll
    for (int k = 0; k < 8; ++k)
        acc[k] += __shfl_xor(acc[k], 4);

    f32x4 st;
    st.x = acc[side * 4 + 0];
    st.y = acc[side * 4 + 1];
    st.z = acc[side * 4 + 2];
    st.w = acc[side * 4 + 3];
    const size_t onqh = ((size_t)n * Lq + q) * NH + h;
    __builtin_nontemporal_store(st, (f32x4*)(out + onqh * DD + cg * 8 + side * 4));
}

// ---------------- fp32 fallback if ws too small ----------------
__global__ __launch_bounds__(256) void msda_fwd_f32(
    const float* __restrict__ value,
    const int*   __restrict__ spatial_shapes,
    const int*   __restrict__ level_start,
    const float* __restrict__ sloc,
    const float* __restrict__ aw,
    float*       __restrict__ out,
    int N, int Lq, int Lin, int total)
{
    int tid = blockIdx.x * blockDim.x + threadIdx.x;
    if (tid >= total) return;
    const int c  = tid & 7;
    const int h  = (tid >> 3) & 7;
    const int nq = tid >> 6;
    const int n  = nq / Lq;
    const bool is64 = (spatial_shapes[1] == 0);
    int Hs[LL], Ws[LL], Ss[LL];
#pragma unroll
    for (int l = 0; l < LL; ++l) {
        if (is64) { Hs[l] = spatial_shapes[4*l]; Ws[l] = spatial_shapes[4*l+2]; Ss[l] = level_start[2*l]; }
        else      { Hs[l] = spatial_shapes[2*l]; Ws[l] = spatial_shapes[2*l+1]; Ss[l] = level_start[l]; }
    }
    const size_t nqh = (size_t)nq * NH + h;
    const float* loc_p = sloc + nqh * (LL * PP * 2);
    const float* aw_p  = aw   + nqh * (LL * PP);
    float4 acc = make_float4(0.f, 0.f, 0.f, 0.f);
#pragma unroll
    for (int l = 0; l < LL; ++l) {
        const int H = Hs[l], W = Ws[l];
        const float* vb = value + (((size_t)n * Lin + Ss[l]) * NH + h) * DD + c * 4;
#pragma unroll
        for (int p = 0; p < PP; ++p) {
            const int jj = l * PP + p;
            const float x = loc_p[2*jj] * (float)W - 0.5f;
            const float y = loc_p[2*jj+1] * (float)H - 0.5f;
            const float w = aw_p[jj];
            const float x0f = floorf(x), y0f = floorf(y);
            const int x0 = (int)x0f, y0 = (int)y0f, x1 = x0+1, y1 = y0+1;
            const float dx = x - x0f, dy = y - y0f;
            const bool vx0 = x0>=0 && x0<W, vx1 = x1>=0 && x1<W;
            const bool vy0 = y0>=0 && y0<H, vy1 = y1>=0 && y1<H;
            const int cx0 = min(max(x0,0),W-1), cx1 = min(max(x1,0),W-1);
            const int cy0 = min(max(y0,0),H-1), cy1 = min(max(y1,0),H-1);
            const float w00 = (1.f-dx)*(1.f-dy)*w*((vx0&&vy0)?1.f:0.f);
            const float w01 = dx*(1.f-dy)*w*((vx1&&vy0)?1.f:0.f);
            const float w10 = (1.f-dx)*dy*w*((vx0&&vy1)?1.f:0.f);
            const float w11 = dx*dy*w*((vx1&&vy1)?1.f:0.f);
            const float4 v00 = *(const float4*)(vb + (size_t)(cy0*W+cx0)*(NH*DD));
            const float4 v01 = *(const float4*)(vb + (size_t)(cy0*W+cx1)*(NH*DD));
            const float4 v10 = *(const float4*)(vb + (size_t)(cy1*W+cx0)*(NH*DD));
            const float4 v11 = *(const float4*)(vb + (size_t)(cy1*W+cx1)*(NH*DD));
            acc.x += w00*v00.x + w01*v01.x + w10*v10.x + w11*v11.x;
            acc.y += w00*v00.y + w01*v01.y + w10*v10.y + w11*v11.y;
            acc.z += w00*v00.z + w01*v01.z + w10*v10.z + w11*v11.z;
            acc.w += w00*v00.w + w01*v01.w + w10*v10.w + w11*v11.w;
        }
    }
    *(float4*)(out + nqh * DD + c * 4) = acc;
}

extern "C" void kernel_launch(void* const* d_in, const int* in_sizes, int n_in,
                              void* d_out, int out_size, void* d_ws, size_t ws_size,
                              hipStream_t stream)
{
    const float* value = (const float*)d_in[0];
    const int*   ss    = (const int*)  d_in[1];
    const int*   lsi   = (const int*)  d_in[2];
    const float* sloc  = (const float*)d_in[3];
    const float* aw    = (const float*)d_in[4];
    float* out = (float*)d_out;

    const int N = 2;
    const int Lq  = in_sizes[4] / (N * NH * LL * PP);
    const int Lin = in_sizes[0] / (N * NH * DD);

    const size_t need = (size_t)N * NH * Lin * DD * sizeof(_Float16);
    if (ws_size >= need) {
        _Float16* vh = (_Float16*)d_ws;
        const int nSlabs = N * NH;              // 16
        const int spx    = (nSlabs + 7) / 8;    // slabs per XCD = 2
        const int segs   = (Lin * 8 + 255) / 256;
        conv_kernel<<<8 * spx * segs, 256, 0, stream>>>(value, vh, Lin, spx, nSlabs);

        const int chunks = (Lq + 31) / 32;
        const int grid   = 8 * spx * chunks;
        msda_fwd_h<<<grid, 256, 0, stream>>>(vh, ss, lsi, sloc, aw, out,
                                             N, Lq, Lin, spx, chunks, nSlabs);
    } else {
        const int total = N * Lq * NH * 8;
        msda_fwd_f32<<<(total + 255) / 256, 256, 0, stream>>>(value, ss, lsi, sloc, aw, out,
                                                              N, Lq, Lin, total);
    }
}